// Round 1
// baseline (8558.028 us; speedup 1.0000x reference)
//
#include <hip/hip_runtime.h>

#define T_STEPS 1000
#define BATCH   256
#define IN_DIM  128
#define HID     512
#define OUT_DIM 32
#define ALPHA_F 0.2f
#define OMA_F   0.8f
#define MAXNNZ  96   // Binomial(511,0.1) max over 512 rows ~ 75; 96 is 6.5 sigma

// ---- workspace layout (byte offsets, all 16B aligned) ----
// val_t : float  [HID][MAXNNZ]   rank-ordered rows      @ 0        (196608 B)
// idx_t : ushort [HID][MAXNNZ]   byte offsets (j*4)     @ 196608   (98304 B)
// perm  : uint   [HID]           rank -> row            @ 294912   (2048 B)
// nnzR  : uint   [HID]           nnz sorted ascending   @ 296960   (2048 B)
// w_inT : float  [IN_DIM][HID]                          @ 299008   (262144 B)
// fcT   : float  [HID][OUT_DIM]                         @ 561152   (65536 B)

// ============================================================
// K2: build sparse table (rank-sorted by nnz) + transposes
// ============================================================
__global__ __launch_bounds__(512) void build_kernel(
    const float* __restrict__ w_h, const float* __restrict__ dale,
    const float* __restrict__ sparse, const float* __restrict__ w_in,
    const float* __restrict__ fc_w,
    float* __restrict__ val_t, unsigned short* __restrict__ idx_t,
    unsigned int* __restrict__ perm, unsigned int* __restrict__ nnzR,
    float* __restrict__ w_inT, float* __restrict__ fcT)
{
    int tid = threadIdx.x;           // 0..511 = row h
    __shared__ int hist[MAXNNZ + 1];
    __shared__ int offs[MAXNNZ + 1];

    const float4* wr4 = (const float4*)(w_h    + tid * HID);
    const float4* sr4 = (const float4*)(sparse + tid * HID);

    // pass 1: count nnz of row h
    int cnt = 0;
    for (int j4 = 0; j4 < HID / 4; j4++) {
        float4 w = wr4[j4];
        float4 s = sr4[j4];
        if (w.x > 0.f && s.x > 0.5f) cnt++;
        if (w.y > 0.f && s.y > 0.5f) cnt++;
        if (w.z > 0.f && s.z > 0.5f) cnt++;
        if (w.w > 0.f && s.w > 0.5f) cnt++;
    }
    int c = min(cnt, MAXNNZ);

    if (tid <= MAXNNZ) hist[tid] = 0;
    __syncthreads();
    atomicAdd(&hist[c], 1);
    __syncthreads();
    if (tid == 0) {
        int a = 0;
        for (int i = 0; i <= MAXNNZ; i++) { offs[i] = a; a += hist[i]; }
    }
    __syncthreads();
    int rank = atomicAdd(&offs[c], 1);
    perm[rank] = (unsigned int)tid;
    nnzR[rank] = (unsigned int)c;

    // pass 2: fill row table at rank-ordered position
    float*          vout = val_t + rank * MAXNNZ;
    unsigned short* iout = idx_t + rank * MAXNNZ;
    int k = 0;
    for (int j = 0; j < HID && k < MAXNNZ; j++) {
        float w = w_h[tid * HID + j];
        float s = sparse[tid * HID + j];
        if (w > 0.f && s > 0.5f) {
            vout[k] = w * dale[j];
            iout[k] = (unsigned short)(j * 4);   // LDS byte offset
            k++;
        }
    }
    for (; k < MAXNNZ; k++) { vout[k] = 0.f; iout[k] = 0; }

    // w_inT[k][n] = w_in[n][k]  (n = tid)
    for (int kk = 0; kk < IN_DIM; kk++)
        w_inT[kk * HID + tid] = w_in[tid * IN_DIM + kk];
    // fcT[k][o] = fc_w[o][k]  (k = tid)
    for (int o = 0; o < OUT_DIM; o++)
        fcT[tid * OUT_DIM + o] = fc_w[o * HID + tid];
}

// ============================================================
// K1: xd[m][h] = x[m]@w_in^T + b_in + b_h  into activity slab
//     m-tile 256 (thread per row), LDS-staged x, scalar w loads
// ============================================================
__global__ __launch_bounds__(256) void ingemm_kernel(
    const float* __restrict__ x, const float* __restrict__ w_inT,
    const float* __restrict__ b_in, const float* __restrict__ b_h,
    float* __restrict__ xd)
{
    __shared__ float xl[256 * 132];   // pad 128->132 to spread banks
    int tid = threadIdx.x;
    long m0 = (long)blockIdx.x * 256;

    const float4* xg = (const float4*)(x + m0 * IN_DIM);
#pragma unroll
    for (int i = 0; i < 32; i++) {
        int f = tid + i * 256;            // 0..8191 float4s
        int r = f >> 5, cc = f & 31;
        float4 v = xg[f];
        *(float4*)(&xl[r * 132 + cc * 4]) = v;
    }
    __syncthreads();

    const float* xrow = &xl[tid * 132];
    for (int nc = 0; nc < 16; nc++) {
        int n0 = nc * 32;
        float acc[32];
#pragma unroll
        for (int j = 0; j < 32; j++) acc[j] = b_in[n0 + j] + b_h[n0 + j];
#pragma unroll 4
        for (int kk = 0; kk < IN_DIM; kk++) {
            float a = xrow[kk];
            const float* wrow = w_inT + kk * HID + n0;   // uniform -> s_load
#pragma unroll
            for (int j = 0; j < 32; j++) acc[j] = fmaf(a, wrow[j], acc[j]);
        }
        float* orow = xd + (m0 + tid) * HID + n0;
#pragma unroll
        for (int j = 0; j < 8; j++)
            *(float4*)(orow + j * 4) =
                make_float4(acc[4*j], acc[4*j+1], acc[4*j+2], acc[4*j+3]);
    }
}

// ============================================================
// K3: the scan. 256 blocks (one batch row each) x 512 threads.
//     Sparse w_eff row in registers, act vector double-buffered
//     in LDS, xd read from / act written to activity slab in place.
// ============================================================
__global__ __launch_bounds__(512, 2) void scan_kernel(
    float* __restrict__ act_g,
    const float* __restrict__ val_t, const unsigned short* __restrict__ idx_t,
    const unsigned int* __restrict__ perm, const unsigned int* __restrict__ nnzR)
{
    int tid = threadIdx.x;       // rank r
    int b   = blockIdx.x;
    __shared__ float sbuf[1024];  // [0..511] region0, [512..1023] region1
    sbuf[tid] = 0.f;

    // load this rank's table into registers (static indexing only)
    float        val[MAXNNZ];
    unsigned int idp[MAXNNZ / 2];
    {
        const float4* vp = (const float4*)(val_t + tid * MAXNNZ);
#pragma unroll
        for (int i = 0; i < MAXNNZ / 4; i++) {
            float4 v = vp[i];
            val[4*i] = v.x; val[4*i+1] = v.y; val[4*i+2] = v.z; val[4*i+3] = v.w;
        }
        const uint4* ip = (const uint4*)(idx_t + tid * MAXNNZ); // 96 u16 = 12 uint4
#pragma unroll
        for (int i = 0; i < MAXNNZ / 8; i++) {
            uint4 u = ip[i];
            idp[4*i] = u.x; idp[4*i+1] = u.y; idp[4*i+2] = u.z; idp[4*i+3] = u.w;
        }
    }
    int h = (int)perm[tid];
    int wmax = (int)nnzR[tid | 63];                 // sorted ascending -> wave max
    wmax = __builtin_amdgcn_readfirstlane(wmax);
    int trip = (wmax + 1) >> 1;                     // pair iterations

    float state = 0.f;
    int gi = b * HID + h;                           // index of (t=0, b, h)
    float xdv = act_g[gi];                          // prefetch t=0
    const char* sb = (const char*)sbuf;
    __syncthreads();

    for (int t = 0; t < T_STEPS; t += 2) {
        { // even step: read region0, write region1
            float xn = act_g[gi + BATCH * HID];     // t+1 <= 999 always here
            float a0 = xdv, a1 = 0.f;
#pragma unroll
            for (int ii = 0; ii < MAXNNZ / 2; ii++) {
                if (ii >= trip) break;              // wave-uniform
                unsigned int pk = idp[ii];
                float g0 = *(const float*)(sb + (pk & 0xffffu));
                float g1 = *(const float*)(sb + (pk >> 16));
                a0 = fmaf(val[2*ii],     g0, a0);
                a1 = fmaf(val[2*ii + 1], g1, a1);
            }
            state = state * OMA_F + (a0 + a1) * ALPHA_F;
            float act = fmaxf(state, 0.f);
            sbuf[512 + h] = act;
            act_g[gi] = act;
            gi += BATCH * HID;
            xdv = xn;
            __syncthreads();
        }
        { // odd step: read region1 (+2048B), write region0
            int gn = (t < T_STEPS - 2) ? gi + BATCH * HID : gi;
            float xn = act_g[gn];
            float a0 = xdv, a1 = 0.f;
#pragma unroll
            for (int ii = 0; ii < MAXNNZ / 2; ii++) {
                if (ii >= trip) break;
                unsigned int pk = idp[ii];
                float g0 = *(const float*)(sb + 2048 + (pk & 0xffffu));
                float g1 = *(const float*)(sb + 2048 + (pk >> 16));
                a0 = fmaf(val[2*ii],     g0, a0);
                a1 = fmaf(val[2*ii + 1], g1, a1);
            }
            state = state * OMA_F + (a0 + a1) * ALPHA_F;
            float act = fmaxf(state, 0.f);
            sbuf[h] = act;
            act_g[gi] = act;
            gi += BATCH * HID;
            xdv = xn;
            __syncthreads();
        }
    }
}

// ============================================================
// K4: out[m][o] = act[m]@fc_w^T + fc_b
// ============================================================
__global__ __launch_bounds__(256) void outgemm_kernel(
    const float* __restrict__ act_g, const float* __restrict__ fcT,
    const float* __restrict__ fc_b, float* __restrict__ out_g)
{
    __shared__ float al[256 * 68];    // k-tile 64, pad ->68
    int tid = threadIdx.x;
    long m0 = (long)blockIdx.x * 256;

    float acc[32];
#pragma unroll
    for (int o = 0; o < 32; o++) acc[o] = fc_b[o];

    for (int k0 = 0; k0 < HID; k0 += 64) {
        __syncthreads();
#pragma unroll
        for (int i = 0; i < 16; i++) {
            int f = tid + i * 256;        // 0..4095 float4s
            int r = f >> 4, cc = f & 15;
            float4 v = *(const float4*)(act_g + (m0 + r) * HID + k0 + cc * 4);
            *(float4*)(&al[r * 68 + cc * 4]) = v;
        }
        __syncthreads();
        const float* arow = &al[tid * 68];
#pragma unroll 4
        for (int kk = 0; kk < 64; kk++) {
            float a = arow[kk];
            const float* frow = fcT + (k0 + kk) * OUT_DIM;  // uniform -> s_load
#pragma unroll
            for (int o = 0; o < 32; o++) acc[o] = fmaf(a, frow[o], acc[o]);
        }
    }
    float* orow = out_g + (m0 + tid) * OUT_DIM;
#pragma unroll
    for (int j = 0; j < 8; j++)
        *(float4*)(orow + j * 4) =
            make_float4(acc[4*j], acc[4*j+1], acc[4*j+2], acc[4*j+3]);
}

// ============================================================
extern "C" void kernel_launch(void* const* d_in, const int* in_sizes, int n_in,
                              void* d_out, int out_size, void* d_ws, size_t ws_size,
                              hipStream_t stream)
{
    const float* x      = (const float*)d_in[0];
    const float* w_in   = (const float*)d_in[1];
    const float* b_in   = (const float*)d_in[2];
    const float* w_h    = (const float*)d_in[3];
    const float* b_h    = (const float*)d_in[4];
    const float* dale   = (const float*)d_in[5];
    const float* sparse = (const float*)d_in[6];
    const float* fc_w   = (const float*)d_in[7];
    const float* fc_b   = (const float*)d_in[8];

    float* out_g = (float*)d_out;
    float* act_g = out_g + (long)T_STEPS * BATCH * OUT_DIM;  // rnn_activity slab

    char* ws = (char*)d_ws;
    float*          val_t = (float*)(ws + 0);
    unsigned short* idx_t = (unsigned short*)(ws + 196608);
    unsigned int*   perm  = (unsigned int*)(ws + 294912);
    unsigned int*   nnzR  = (unsigned int*)(ws + 296960);
    float*          w_inT = (float*)(ws + 299008);
    float*          fcT   = (float*)(ws + 561152);

    build_kernel<<<1, 512, 0, stream>>>(w_h, dale, sparse, w_in, fc_w,
                                        val_t, idx_t, perm, nnzR, w_inT, fcT);
    ingemm_kernel<<<1000, 256, 0, stream>>>(x, w_inT, b_in, b_h, act_g);
    scan_kernel<<<256, 512, 0, stream>>>(act_g, val_t, idx_t, perm, nnzR);
    outgemm_kernel<<<1000, 256, 0, stream>>>(act_g, fcT, fc_b, out_g);
}

// Round 2
// 3211.898 us; speedup vs baseline: 2.6645x; 2.6645x over previous
//
#include <hip/hip_runtime.h>

#define T_STEPS 1000
#define BATCH   256
#define IN_DIM  128
#define HID     512
#define OUT_DIM 32
#define ALPHA_F 0.2f
#define OMA_F   0.8f
#define MAXNNZ  96   // Binomial(511,0.1) max over 512 rows ~ 75; 96 is 6.5 sigma

// ---- workspace layout (byte offsets, all 16B aligned) ----
// val_t : float  [HID][MAXNNZ]   rank-ordered rows      @ 0        (196608 B)
// idx_t : ushort [HID][MAXNNZ]   byte offsets (j*4)     @ 196608   (98304 B)
// perm  : uint   [HID]           rank -> row            @ 294912   (2048 B)
// nnzR  : uint   [HID]           nnz sorted ascending   @ 296960   (2048 B)
// w_inT : float  [IN_DIM][HID]                          @ 299008   (262144 B)
// fcT   : float  [HID][OUT_DIM]                         @ 561152   (65536 B)

// ============================================================
// K2: build sparse table (rank-sorted by nnz) + transposes
// ============================================================
__global__ __launch_bounds__(512) void build_kernel(
    const float* __restrict__ w_h, const float* __restrict__ dale,
    const float* __restrict__ sparse, const float* __restrict__ w_in,
    const float* __restrict__ fc_w,
    float* __restrict__ val_t, unsigned short* __restrict__ idx_t,
    unsigned int* __restrict__ perm, unsigned int* __restrict__ nnzR,
    float* __restrict__ w_inT, float* __restrict__ fcT)
{
    int tid = threadIdx.x;           // 0..511 = row h
    __shared__ int hist[MAXNNZ + 1];
    __shared__ int offs[MAXNNZ + 1];

    const float4* wr4 = (const float4*)(w_h    + tid * HID);
    const float4* sr4 = (const float4*)(sparse + tid * HID);

    // pass 1: count nnz of row h
    int cnt = 0;
    for (int j4 = 0; j4 < HID / 4; j4++) {
        float4 w = wr4[j4];
        float4 s = sr4[j4];
        if (w.x > 0.f && s.x > 0.5f) cnt++;
        if (w.y > 0.f && s.y > 0.5f) cnt++;
        if (w.z > 0.f && s.z > 0.5f) cnt++;
        if (w.w > 0.f && s.w > 0.5f) cnt++;
    }
    int c = min(cnt, MAXNNZ);

    if (tid <= MAXNNZ) hist[tid] = 0;
    __syncthreads();
    atomicAdd(&hist[c], 1);
    __syncthreads();
    if (tid == 0) {
        int a = 0;
        for (int i = 0; i <= MAXNNZ; i++) { offs[i] = a; a += hist[i]; }
    }
    __syncthreads();
    int rank = atomicAdd(&offs[c], 1);
    perm[rank] = (unsigned int)tid;
    nnzR[rank] = (unsigned int)c;

    // pass 2: fill row table at rank-ordered position
    float*          vout = val_t + rank * MAXNNZ;
    unsigned short* iout = idx_t + rank * MAXNNZ;
    int k = 0;
    for (int j = 0; j < HID && k < MAXNNZ; j++) {
        float w = w_h[tid * HID + j];
        float s = sparse[tid * HID + j];
        if (w > 0.f && s > 0.5f) {
            vout[k] = w * dale[j];
            iout[k] = (unsigned short)(j * 4);   // LDS byte offset
            k++;
        }
    }
    for (; k < MAXNNZ; k++) { vout[k] = 0.f; iout[k] = 0; }

    // w_inT[k][n] = w_in[n][k]  (n = tid)
    for (int kk = 0; kk < IN_DIM; kk++)
        w_inT[kk * HID + tid] = w_in[tid * IN_DIM + kk];
    // fcT[k][o] = fc_w[o][k]  (k = tid)
    for (int o = 0; o < OUT_DIM; o++)
        fcT[tid * OUT_DIM + o] = fc_w[o * HID + tid];
}

// ============================================================
// K1: xd[m][h] = x[m]@w_in^T + b_in + b_h  into activity slab
// ============================================================
__global__ __launch_bounds__(256) void ingemm_kernel(
    const float* __restrict__ x, const float* __restrict__ w_inT,
    const float* __restrict__ b_in, const float* __restrict__ b_h,
    float* __restrict__ xd)
{
    __shared__ float xl[256 * 132];   // pad 128->132 to spread banks
    int tid = threadIdx.x;
    long m0 = (long)blockIdx.x * 256;

    const float4* xg = (const float4*)(x + m0 * IN_DIM);
#pragma unroll
    for (int i = 0; i < 32; i++) {
        int f = tid + i * 256;            // 0..8191 float4s
        int r = f >> 5, cc = f & 31;
        float4 v = xg[f];
        *(float4*)(&xl[r * 132 + cc * 4]) = v;
    }
    __syncthreads();

    const float* xrow = &xl[tid * 132];
    for (int nc = 0; nc < 16; nc++) {
        int n0 = nc * 32;
        float acc[32];
#pragma unroll
        for (int j = 0; j < 32; j++) acc[j] = b_in[n0 + j] + b_h[n0 + j];
#pragma unroll 4
        for (int kk = 0; kk < IN_DIM; kk++) {
            float a = xrow[kk];
            const float* wrow = w_inT + kk * HID + n0;   // uniform -> s_load
#pragma unroll
            for (int j = 0; j < 32; j++) acc[j] = fmaf(a, wrow[j], acc[j]);
        }
        float* orow = xd + (m0 + tid) * HID + n0;
#pragma unroll
        for (int j = 0; j < 8; j++)
            *(float4*)(orow + j * 4) =
                make_float4(acc[4*j], acc[4*j+1], acc[4*j+2], acc[4*j+3]);
    }
}

// ============================================================
// K3: the scan. 256 blocks (one batch row each) x 512 threads.
//     Sparse w_eff row in REGISTERS (all-static indexing via
//     fallthrough switch on wave-uniform chunk count), act vector
//     double-buffered in LDS.
// ============================================================

// one packed pair: 2 gathers + 2 fmas, indices compile-time constant
#define PAIR2(base, ii)                                              \
    {                                                                \
        unsigned int pk = idp[ii];                                   \
        float g0 = *(const float*)((base) + (pk & 0xffffu));         \
        float g1 = *(const float*)((base) + (pk >> 16));             \
        a0 = fmaf(val[2*(ii)],     g0, a0);                          \
        a1 = fmaf(val[2*(ii) + 1], g1, a1);                          \
    }

#define CHUNK4(base, c)                                              \
    PAIR2(base, 4*(c)+0) PAIR2(base, 4*(c)+1)                        \
    PAIR2(base, 4*(c)+2) PAIR2(base, 4*(c)+3)

// accumulate a0+a1 over nch chunks (8 elements each), descending
// chunk order via fallthrough — every array index is a literal.
__device__ __forceinline__ float sparse_accum(
    const char* base, const float (&val)[MAXNNZ],
    const unsigned int (&idp)[MAXNNZ / 2], int nch, float a_init)
{
    float a0 = a_init, a1 = 0.f;
    switch (nch) {
        case 12: CHUNK4(base, 11) [[fallthrough]];
        case 11: CHUNK4(base, 10) [[fallthrough]];
        case 10: CHUNK4(base,  9) [[fallthrough]];
        case  9: CHUNK4(base,  8) [[fallthrough]];
        case  8: CHUNK4(base,  7) [[fallthrough]];
        case  7: CHUNK4(base,  6) [[fallthrough]];
        case  6: CHUNK4(base,  5) [[fallthrough]];
        case  5: CHUNK4(base,  4) [[fallthrough]];
        case  4: CHUNK4(base,  3) [[fallthrough]];
        case  3: CHUNK4(base,  2) [[fallthrough]];
        case  2: CHUNK4(base,  1) [[fallthrough]];
        case  1: CHUNK4(base,  0) break;
        default: break;
    }
    return a0 + a1;
}

__global__ __launch_bounds__(512, 2) void scan_kernel(
    float* __restrict__ act_g,
    const float* __restrict__ val_t, const unsigned short* __restrict__ idx_t,
    const unsigned int* __restrict__ perm, const unsigned int* __restrict__ nnzR)
{
    int tid = threadIdx.x;       // rank r
    int b   = blockIdx.x;
    __shared__ float sbuf[1024];  // [0..511] region0, [512..1023] region1
    sbuf[tid] = 0.f;

    // load this rank's table into registers (static indexing only)
    float        val[MAXNNZ];
    unsigned int idp[MAXNNZ / 2];
    {
        const float4* vp = (const float4*)(val_t + tid * MAXNNZ);
#pragma unroll
        for (int i = 0; i < MAXNNZ / 4; i++) {
            float4 v = vp[i];
            val[4*i] = v.x; val[4*i+1] = v.y; val[4*i+2] = v.z; val[4*i+3] = v.w;
        }
        const uint4* ip = (const uint4*)(idx_t + tid * MAXNNZ); // 96 u16 = 12 uint4
#pragma unroll
        for (int i = 0; i < MAXNNZ / 8; i++) {
            uint4 u = ip[i];
            idp[4*i] = u.x; idp[4*i+1] = u.y; idp[4*i+2] = u.z; idp[4*i+3] = u.w;
        }
    }
    int h = (int)perm[tid];
    int wmax = (int)nnzR[tid | 63];                 // sorted ascending -> wave max
    wmax = __builtin_amdgcn_readfirstlane(wmax);
    int nch = (wmax + 7) >> 3;                      // chunks of 8 elems (4 pairs)

    float state = 0.f;
    int gi = b * HID + h;                           // index of (t=0, b, h)
    float xdv = act_g[gi];                          // prefetch t=0
    const char* sb = (const char*)sbuf;
    __syncthreads();

    for (int t = 0; t < T_STEPS; t += 2) {
        { // even step: read region0, write region1
            float xn = act_g[gi + BATCH * HID];     // t+1 <= 999 always here
            float a = sparse_accum(sb, val, idp, nch, xdv);
            state = state * OMA_F + a * ALPHA_F;
            float act = fmaxf(state, 0.f);
            sbuf[512 + h] = act;
            act_g[gi] = act;
            gi += BATCH * HID;
            xdv = xn;
            __syncthreads();
        }
        { // odd step: read region1 (+2048B), write region0
            int gn = (t < T_STEPS - 2) ? gi + BATCH * HID : gi;
            float xn = act_g[gn];
            float a = sparse_accum(sb + 2048, val, idp, nch, xdv);
            state = state * OMA_F + a * ALPHA_F;
            float act = fmaxf(state, 0.f);
            sbuf[h] = act;
            act_g[gi] = act;
            gi += BATCH * HID;
            xdv = xn;
            __syncthreads();
        }
    }
}

// ============================================================
// K4: out[m][o] = act[m]@fc_w^T + fc_b
// ============================================================
__global__ __launch_bounds__(256) void outgemm_kernel(
    const float* __restrict__ act_g, const float* __restrict__ fcT,
    const float* __restrict__ fc_b, float* __restrict__ out_g)
{
    __shared__ float al[256 * 68];    // k-tile 64, pad ->68
    int tid = threadIdx.x;
    long m0 = (long)blockIdx.x * 256;

    float acc[32];
#pragma unroll
    for (int o = 0; o < 32; o++) acc[o] = fc_b[o];

    for (int k0 = 0; k0 < HID; k0 += 64) {
        __syncthreads();
#pragma unroll
        for (int i = 0; i < 16; i++) {
            int f = tid + i * 256;        // 0..4095 float4s
            int r = f >> 4, cc = f & 15;
            float4 v = *(const float4*)(act_g + (m0 + r) * HID + k0 + cc * 4);
            *(float4*)(&al[r * 68 + cc * 4]) = v;
        }
        __syncthreads();
        const float* arow = &al[tid * 68];
#pragma unroll 4
        for (int kk = 0; kk < 64; kk++) {
            float a = arow[kk];
            const float* frow = fcT + (k0 + kk) * OUT_DIM;  // uniform -> s_load
#pragma unroll
            for (int o = 0; o < 32; o++) acc[o] = fmaf(a, frow[o], acc[o]);
        }
    }
    float* orow = out_g + (m0 + tid) * OUT_DIM;
#pragma unroll
    for (int j = 0; j < 8; j++)
        *(float4*)(orow + j * 4) =
            make_float4(acc[4*j], acc[4*j+1], acc[4*j+2], acc[4*j+3]);
}

// ============================================================
extern "C" void kernel_launch(void* const* d_in, const int* in_sizes, int n_in,
                              void* d_out, int out_size, void* d_ws, size_t ws_size,
                              hipStream_t stream)
{
    const float* x      = (const float*)d_in[0];
    const float* w_in   = (const float*)d_in[1];
    const float* b_in   = (const float*)d_in[2];
    const float* w_h    = (const float*)d_in[3];
    const float* b_h    = (const float*)d_in[4];
    const float* dale   = (const float*)d_in[5];
    const float* sparse = (const float*)d_in[6];
    const float* fc_w   = (const float*)d_in[7];
    const float* fc_b   = (const float*)d_in[8];

    float* out_g = (float*)d_out;
    float* act_g = out_g + (long)T_STEPS * BATCH * OUT_DIM;  // rnn_activity slab

    char* ws = (char*)d_ws;
    float*          val_t = (float*)(ws + 0);
    unsigned short* idx_t = (unsigned short*)(ws + 196608);
    unsigned int*   perm  = (unsigned int*)(ws + 294912);
    unsigned int*   nnzR  = (unsigned int*)(ws + 296960);
    float*          w_inT = (float*)(ws + 299008);
    float*          fcT   = (float*)(ws + 561152);

    build_kernel<<<1, 512, 0, stream>>>(w_h, dale, sparse, w_in, fc_w,
                                        val_t, idx_t, perm, nnzR, w_inT, fcT);
    ingemm_kernel<<<1000, 256, 0, stream>>>(x, w_inT, b_in, b_h, act_g);
    scan_kernel<<<256, 512, 0, stream>>>(act_g, val_t, idx_t, perm, nnzR);
    outgemm_kernel<<<1000, 256, 0, stream>>>(act_g, fcT, fc_b, out_g);
}